// Round 1
// 152.635 us; speedup vs baseline: 1.0024x; 1.0024x over previous
//
#include <hip/hip_runtime.h>
#include <cstdint>

// B,D,H,W,C = 4,8,16,16,512; R=64; F=256; rows=8192; keys/batch=2048.
// v2 restructure:
//   k0: pack weights only: wqkv (640-col fused [wq|wk|wv]) + wm, bf16 frag panels.
//   k1: fused QKV projection GEMM (8192 x 640 = x @ [wq|wk|wv]); 32 rows/block,
//       256 blocks x 512 thr; writes Q/K frag panels and V in B-operand frag
//       layout (key-inner) -> Vb. 2-phase stage-early double-buffered K-loop.
//   k234: attn = a2 @ V (K=256) replaces old (a2@x)@wv  -> 40 staged steps vs 56,
//       no 8MB x repack. 32 rows/block (256 blocks, 8 waves = 2rg x 4cg).
//       All K-loops: glds(s+1) issued BEFORE MFMA(s), ONE __syncthreads per step.
//   XCD decode: bid = ftile*32 + bd so the 8 blocks of a bd share one XCD's L2.
#define LN_EPS 1e-3f
using u16 = unsigned short;
using u32 = unsigned int;
typedef __attribute__((ext_vector_type(8))) short bh8;   // 8 bf16
typedef __attribute__((ext_vector_type(4))) float f4;    // 4 f32 acc
#define MFMA16(A,B,C) __builtin_amdgcn_mfma_f32_16x16x32_bf16((A),(B),(C),0,0,0)

__device__ __forceinline__ u16 bf16r(float f){
    union{float f;u32 u;} c; c.f=f;
    return (u16)((c.u + 0x7fffu + ((c.u>>16)&1u))>>16);
}
__device__ __forceinline__ u32 pk2(float a, float b){
    return (u32)bf16r(a) | ((u32)bf16r(b)<<16);
}
__device__ __forceinline__ void glds16(const void* g, void* l){
    __builtin_amdgcn_global_load_lds(
        (const __attribute__((address_space(1))) u32*)g,
        (__attribute__((address_space(3))) u32*)l, 16, 0, 0);
}

// ---------------- K0: pack weights -> bf16 frag-ordered B panels ----------------
// blocks 0..31: wqkv (16 K-steps x 2 halves), 640 cols: [wq(64)|wk(64)|wv(512)]
// blocks 32..63: wm (16 K-steps x 2 halves), 512 cols
__global__ __launch_bounds__(256) void k0_prep(
    const float* __restrict__ wq, const float* __restrict__ wk,
    const float* __restrict__ wv, const float* __restrict__ wm,
    u16* __restrict__ wqkv_p, u16* __restrict__ wm_p)
{
    const int t = threadIdx.x;
    const int c = t & 15, qn = t >> 4;
    const int quad = qn & 3, ntl = qn >> 2;   // ntl 0..3
    const int blk = blockIdx.x;
    if (blk < 32){
        const int s = blk >> 1, hh = blk & 1;
        const int krow = s*32 + quad*8;
        u16* dst = wqkv_p + (size_t)s*20480;
        #pragma unroll
        for (int i=0;i<5;++i){
            const int nt = hh*20 + i*4 + ntl;
            const int n = nt*16 + c;
            const float* src; int ldw;
            if (n < 64){ src = wq + (size_t)krow*64 + n; ldw = 64; }
            else if (n < 128){ src = wk + (size_t)krow*64 + (n-64); ldw = 64; }
            else { src = wv + (size_t)krow*512 + (n-128); ldw = 512; }
            float v[8];
            #pragma unroll
            for (int j=0;j<8;++j) v[j] = src[(size_t)j*ldw];
            uint4 o; o.x=pk2(v[0],v[1]); o.y=pk2(v[2],v[3]); o.z=pk2(v[4],v[5]); o.w=pk2(v[6],v[7]);
            *(uint4*)&dst[((nt*4+quad)*16 + c)*8] = o;
        }
    } else {
        const int bb = blk - 32;
        const int s = bb >> 1, hh = bb & 1;
        const int krow = s*32 + quad*8;
        u16* dst = wm_p + (size_t)s*16384;
        #pragma unroll
        for (int i=0;i<4;++i){
            const int nt = hh*16 + i*4 + ntl;
            const int n = nt*16 + c;
            const float* src = wm + (size_t)krow*512 + n;
            float v[8];
            #pragma unroll
            for (int j=0;j<8;++j) v[j] = src[(size_t)j*512];
            uint4 o; o.x=pk2(v[0],v[1]); o.y=pk2(v[2],v[3]); o.z=pk2(v[4],v[5]); o.w=pk2(v[6],v[7]);
            *(uint4*)&dst[((nt*4+quad)*16 + c)*8] = o;
        }
    }
}

// ---------------- K1: fused QKV projection ----------------
// 256 blocks x 512 thr; 32 rows/block; N=640 (Q64|K64|V512); K=512 in 16 steps.
__global__ __launch_bounds__(512) void k1_qkv(
    const float* __restrict__ x, const float* __restrict__ bq, const float* __restrict__ bk,
    const u16* __restrict__ wqkv_p,
    u16* __restrict__ Qb, u16* __restrict__ Kb, u16* __restrict__ Vb)
{
    __shared__ u16 Asf[16384];      // 32 KB: 2 rg-tiles x 16 s x 512 (A frags)
    __shared__ u16 Bs[2][20480];    // 2 x 40 KB ring
    const int t = threadIdx.x, w = t>>6, lane = t&63, quad = (lane>>4)&3, c = lane&15;
    const int rg = w>>2, cg = w&3;
    const int rowbase = blockIdx.x << 5;

    // stage A (32 rows x 512 f32 -> bf16 frag order), coalesced float4
    #pragma unroll
    for (int i=0;i<8;++i){
        const int idx = t + (i<<9);            // 0..4095 float4 units
        const int fr = idx >> 7, fc4 = idx & 127;
        float4 xv = *(const float4*)&x[(size_t)(rowbase+fr)*512 + fc4*4];
        uint2 pkv; pkv.x = pk2(xv.x,xv.y); pkv.y = pk2(xv.z,xv.w);
        const int s = fc4 >> 3, qd = (fc4 >> 1) & 3, j0 = (fc4 & 1)*4;
        *(uint2*)&Asf[(fr>>4)*8192 + s*512 + (qd*16 + (fr&15))*8 + j0] = pkv;
    }
    f4 acc[10];
    #pragma unroll
    for (int i=0;i<10;++i) acc[i] = (f4){0.f,0.f,0.f,0.f};
    // prologue: chunk 0 (overlaps with A-staging drain)
    #pragma unroll
    for (int i=0;i<5;++i)
        glds16((const char*)wqkv_p + (size_t)w*5120 + i*1024 + lane*16,
               (char*)Bs[0] + w*5120 + i*1024);
    __syncthreads();

    for (int s=0;s<16;++s){
        const u16* Bcur = Bs[s&1];
        if (s+1 < 16){
            #pragma unroll
            for (int i=0;i<5;++i)
                glds16((const char*)wqkv_p + (size_t)(s+1)*40960 + (size_t)w*5120 + i*1024 + lane*16,
                       (char*)Bs[(s+1)&1] + w*5120 + i*1024);
        }
        bh8 a = *(const bh8*)&Asf[rg*8192 + s*512 + (quad*16+c)*8];
        #pragma unroll
        for (int nt2=0;nt2<10;++nt2){
            bh8 bb = *(const bh8*)&Bcur[((cg*10+nt2)*4 + quad)*128 + c*8];
            acc[nt2] = MFMA16(a, bb, acc[nt2]);
        }
        __syncthreads();
    }

    // epilogue: Q/K -> frag panels (+bias); V -> B-operand frag layout (no bias)
    const int rt = (blockIdx.x<<1) + rg;
    const int bd = rowbase >> 8;
    const int kloc = (rowbase & 255) + rg*16 + quad*4;     // + reg
    const int sv = kloc >> 5, kq = (kloc >> 3) & 3, jk0 = kloc & 7;  // reg-invariant
    #pragma unroll
    for (int nt2=0;nt2<10;++nt2){
        const int colb = cg*160 + nt2*16;
        if (colb < 128){
            const bool isK = (colb >= 64);
            const int r = colb - (isK ? 64 : 0) + c;
            const float bias = isK ? bk[r] : bq[r];
            u16* dstb = (isK ? Kb : Qb) + ((size_t)(rt*2 + (r>>5))*4 + ((r>>3)&3))*128 + (r&7);
            #pragma unroll
            for (int reg=0;reg<4;++reg)
                dstb[(quad*4+reg)*8] = bf16r(acc[nt2][reg] + bias);
        } else {
            const int ntv = (colb - 128) >> 4;             // channel group; cv = c
            u16* dstv = Vb + (size_t)bd*131072 + (size_t)sv*16384
                           + (size_t)((ntv*4+kq)*128 + c*8 + jk0);
            ushort4 o;
            o.x = bf16r(acc[nt2][0]); o.y = bf16r(acc[nt2][1]);
            o.z = bf16r(acc[nt2][2]); o.w = bf16r(acc[nt2][3]);
            *(ushort4*)dstv = o;
        }
    }
}

// ---------------- K234: scores+softmax-fold, a2@V, LN, y1@wm, LN ----------------
// 256 blocks x 512 thr (8 waves = 2rg x 4cg), 32 rows/block.
__global__ __launch_bounds__(512) void k234(
    const u16* __restrict__ Qb, const u16* __restrict__ Kb, const u16* __restrict__ Vb,
    const u16* __restrict__ wm_p,
    const float* __restrict__ x, const float* __restrict__ bv,
    const float* __restrict__ g1, const float* __restrict__ b1,
    const float* __restrict__ bm, const float* __restrict__ g2, const float* __restrict__ b2,
    float* __restrict__ out)
{
    __shared__ u16 Bs[2][16384];    // 64 KB ring (A uses 16 KB of each buf)
    __shared__ u16 y1f[16384];      // 32 KB: y1 A-frags, 2 rg x 16 s x 512
    __shared__ u16 a2f[8192];       // 16 KB: a2 A-frags, 2 rg x 8 s x 512
    __shared__ u16 qsf[2048];       // 4 KB: Q frags, 2 rts
    __shared__ float redA[2][4][16], redB[2][4][16];
    const int t = threadIdx.x, w = t>>6, lane = t&63, quad = (lane>>4)&3, c = lane&15;
    const int rg = w>>2, cg = w&3;
    const int bd = blockIdx.x & 31, ftile = blockIdx.x >> 5;   // XCD-aligned decode
    const int b = bd >> 3;
    const int rowbase = (bd<<8) + (ftile<<5);
    const int rt00 = rowbase >> 4;
    const char* Kbase = (const char*)Kb + (size_t)b*262144;
    const char* Vbase = (const char*)Vb + (size_t)bd*262144;

    // ---- Phase A prologue: Q frags + key-chunk 0
    if (w < 4) glds16((const char*)Qb + (size_t)rt00*2048 + w*1024 + lane*16,
                      (char*)qsf + w*1024);
    #pragma unroll
    for (int i=0;i<2;++i)
        glds16(Kbase + (size_t)w*2048 + i*1024 + lane*16, (char*)Bs[0] + w*2048 + i*1024);
    __syncthreads();
    bh8 aq0 = *(const bh8*)&qsf[rg*1024 + (quad*16+c)*8];
    bh8 aq1 = *(const bh8*)&qsf[rg*1024 + 512 + (quad*16+c)*8];

    float lp[4] = {0.f,0.f,0.f,0.f};
    float a2r[4][2][2] = {};
    // ---- Phase A: 16 chunks x 128 keys; exp + g-fold
    #pragma unroll
    for (int cc=0; cc<16; ++cc){
        const u16* Bcur = Bs[cc&1];
        if (cc+1 < 16){
            #pragma unroll
            for (int i=0;i<2;++i)
                glds16(Kbase + (size_t)(cc+1)*16384 + (size_t)w*2048 + i*1024 + lane*16,
                       (char*)Bs[(cc+1)&1] + w*2048 + i*1024);
        }
        f4 sa[2] = { (f4){0.f,0.f,0.f,0.f}, (f4){0.f,0.f,0.f,0.f} };
        #pragma unroll
        for (int kt=0;kt<2;++kt){
            bh8 b0 = *(const bh8*)&Bcur[(cg*2+kt)*1024 + (quad*16+c)*8];
            bh8 b1v= *(const bh8*)&Bcur[(cg*2+kt)*1024 + 512 + (quad*16+c)*8];
            sa[kt] = MFMA16(aq0, b0, sa[kt]);
            sa[kt] = MFMA16(aq1, b1v, sa[kt]);
        }
        #pragma unroll
        for (int kt=0;kt<2;++kt)
            #pragma unroll
            for (int reg=0;reg<4;++reg){
                float e = __expf(sa[kt][reg]);
                lp[reg] += e;
                a2r[reg][cc&1][kt] += e;
            }
        __syncthreads();
    }
    // prologue for phase B (V chunk 0) -- overlaps softmax finish
    {
        #pragma unroll
        for (int i=0;i<4;++i)
            glds16(Vbase + (size_t)w*4096 + i*1024 + lane*16, (char*)Bs[0] + w*4096 + i*1024);
    }
    // softmax denominator: reduce over c lanes, then across 4 cg waves
    #pragma unroll
    for (int reg=0;reg<4;++reg){
        float v = lp[reg];
        v += __shfl_xor(v,1,64); v += __shfl_xor(v,2,64);
        v += __shfl_xor(v,4,64); v += __shfl_xor(v,8,64);
        lp[reg] = v;
    }
    if (c==0){
        #pragma unroll
        for (int reg=0;reg<4;++reg) redA[rg][cg][quad*4+reg] = lp[reg];
    }
    __syncthreads();
    float fac[4];
    #pragma unroll
    for (int reg=0;reg<4;++reg){
        const int q = quad*4+reg;
        fac[reg] = 1.f/(redA[rg][0][q]+redA[rg][1][q]+redA[rg][2][q]+redA[rg][3][q]);
    }
    #pragma unroll
    for (int reg=0;reg<4;++reg)
        #pragma unroll
        for (int h=0;h<2;++h)
            #pragma unroll
            for (int kt=0;kt<2;++kt){
                const int jp = h*128 + cg*32 + kt*16 + c;
                a2f[rg*4096 + (jp>>5)*512 + (((jp>>3)&3)*16 + quad*4+reg)*8 + (jp&7)]
                    = bf16r(a2r[reg][h][kt]*fac[reg]);
            }
    __syncthreads();

    // ---- Phase B: attn = a2 @ V  (K=256, 8 steps)
    f4 cacc[8];
    #pragma unroll
    for (int i=0;i<8;++i) cacc[i] = (f4){0.f,0.f,0.f,0.f};
    for (int s8=0;s8<8;++s8){
        const u16* Bcur = Bs[s8&1];
        if (s8+1 < 8){
            #pragma unroll
            for (int i=0;i<4;++i)
                glds16(Vbase + (size_t)(s8+1)*32768 + (size_t)w*4096 + i*1024 + lane*16,
                       (char*)Bs[(s8+1)&1] + w*4096 + i*1024);
        }
        bh8 a = *(const bh8*)&a2f[rg*4096 + s8*512 + (quad*16+c)*8];
        #pragma unroll
        for (int nt2=0;nt2<8;++nt2){
            bh8 bb = *(const bh8*)&Bcur[((cg*8+nt2)*4 + quad)*128 + c*8];
            cacc[nt2] = MFMA16(a, bb, cacc[nt2]);
        }
        __syncthreads();
    }

    // ---- epilogue 1: + bv + x residual, LN -> y1 (kept f32 in cacc, bf16 frags in y1f)
    {
        float sv4[4] = {0.f,0.f,0.f,0.f}, qv2[4] = {0.f,0.f,0.f,0.f};
        #pragma unroll
        for (int nt2=0;nt2<8;++nt2){
            const int col = cg*128 + nt2*16 + c;
            const float bvv = bv[col];
            #pragma unroll
            for (int reg=0;reg<4;++reg){
                const int row = rowbase + rg*16 + quad*4 + reg;
                float val = cacc[nt2][reg] + bvv + x[(size_t)row*512 + col];
                cacc[nt2][reg] = val;
                sv4[reg] += val; qv2[reg] = fmaf(val,val,qv2[reg]);
            }
        }
        #pragma unroll
        for (int reg=0;reg<4;++reg){
            float s1=sv4[reg], s2=qv2[reg];
            s1 += __shfl_xor(s1,1,64); s2 += __shfl_xor(s2,1,64);
            s1 += __shfl_xor(s1,2,64); s2 += __shfl_xor(s2,2,64);
            s1 += __shfl_xor(s1,4,64); s2 += __shfl_xor(s2,4,64);
            s1 += __shfl_xor(s1,8,64); s2 += __shfl_xor(s2,8,64);
            sv4[reg]=s1; qv2[reg]=s2;
        }
        if (c==0){
            #pragma unroll
            for (int reg=0;reg<4;++reg){ redA[rg][cg][quad*4+reg]=sv4[reg]; redB[rg][cg][quad*4+reg]=qv2[reg]; }
        }
        __syncthreads();
        float mean[4], rstd[4];
        #pragma unroll
        for (int reg=0;reg<4;++reg){
            const int q = quad*4+reg;
            const float S  = redA[rg][0][q]+redA[rg][1][q]+redA[rg][2][q]+redA[rg][3][q];
            const float Q2 = redB[rg][0][q]+redB[rg][1][q]+redB[rg][2][q]+redB[rg][3][q];
            const float m = S*(1.f/512.f);
            mean[reg]=m; rstd[reg]=rsqrtf(Q2*(1.f/512.f) - m*m + LN_EPS);
        }
        #pragma unroll
        for (int nt2=0;nt2<8;++nt2){
            const int col = cg*128 + nt2*16 + c;
            const float gg = g1[col], bb1 = b1[col];
            #pragma unroll
            for (int reg=0;reg<4;++reg){
                float y = (cacc[nt2][reg]-mean[reg])*rstd[reg]*gg + bb1;
                cacc[nt2][reg] = y;
                y1f[rg*8192 + (col>>5)*512 + (((col>>3)&3)*16 + quad*4+reg)*8 + (col&7)] = bf16r(y);
            }
        }
        // prologue for phase D (wm chunk 0) -- overlaps epilogue drain
        #pragma unroll
        for (int i=0;i<4;++i)
            glds16((const char*)wm_p + (size_t)w*4096 + i*1024 + lane*16,
                   (char*)Bs[0] + w*4096 + i*1024);
        __syncthreads();
    }

    // ---- Phase D: mlp = y1 @ wm (K=512, 16 steps)
    f4 dacc[8];
    #pragma unroll
    for (int i=0;i<8;++i) dacc[i] = (f4){0.f,0.f,0.f,0.f};
    for (int s=0;s<16;++s){
        const u16* Bcur = Bs[s&1];
        if (s+1 < 16){
            #pragma unroll
            for (int i=0;i<4;++i)
                glds16((const char*)wm_p + (size_t)(s+1)*32768 + (size_t)w*4096 + i*1024 + lane*16,
                       (char*)Bs[(s+1)&1] + w*4096 + i*1024);
        }
        bh8 a = *(const bh8*)&y1f[rg*8192 + s*512 + (quad*16+c)*8];
        #pragma unroll
        for (int nt2=0;nt2<8;++nt2){
            bh8 bb = *(const bh8*)&Bcur[((cg*8+nt2)*4 + quad)*128 + c*8];
            dacc[nt2] = MFMA16(a, bb, dacc[nt2]);
        }
        __syncthreads();
    }

    // ---- epilogue 2: relu(+bm) + y1 residual, LN -> out
    {
        float sv4[4] = {0.f,0.f,0.f,0.f}, qv2[4] = {0.f,0.f,0.f,0.f};
        #pragma unroll
        for (int nt2=0;nt2<8;++nt2){
            const int col = cg*128 + nt2*16 + c;
            const float bmv = bm[col];
            #pragma unroll
            for (int reg=0;reg<4;++reg){
                float hh = fmaxf(dacc[nt2][reg]+bmv, 0.f) + cacc[nt2][reg];
                dacc[nt2][reg] = hh;
                sv4[reg] += hh; qv2[reg] = fmaf(hh,hh,qv2[reg]);
            }
        }
        #pragma unroll
        for (int reg=0;reg<4;++reg){
            float s1=sv4[reg], s2=qv2[reg];
            s1 += __shfl_xor(s1,1,64); s2 += __shfl_xor(s2,1,64);
            s1 += __shfl_xor(s1,2,64); s2 += __shfl_xor(s2,2,64);
            s1 += __shfl_xor(s1,4,64); s2 += __shfl_xor(s2,4,64);
            s1 += __shfl_xor(s1,8,64); s2 += __shfl_xor(s2,8,64);
            sv4[reg]=s1; qv2[reg]=s2;
        }
        if (c==0){
            #pragma unroll
            for (int reg=0;reg<4;++reg){ redA[rg][cg][quad*4+reg]=sv4[reg]; redB[rg][cg][quad*4+reg]=qv2[reg]; }
        }
        __syncthreads();
        float mean[4], rstd[4];
        #pragma unroll
        for (int reg=0;reg<4;++reg){
            const int q = quad*4+reg;
            const float S  = redA[rg][0][q]+redA[rg][1][q]+redA[rg][2][q]+redA[rg][3][q];
            const float Q2 = redB[rg][0][q]+redB[rg][1][q]+redB[rg][2][q]+redB[rg][3][q];
            const float m = S*(1.f/512.f);
            mean[reg]=m; rstd[reg]=rsqrtf(Q2*(1.f/512.f) - m*m + LN_EPS);
        }
        #pragma unroll
        for (int nt2=0;nt2<8;++nt2){
            const int col = cg*128 + nt2*16 + c;
            const float gg = g2[col], bb2 = b2[col];
            #pragma unroll
            for (int reg=0;reg<4;++reg){
                const int row = rowbase + rg*16 + quad*4 + reg;
                out[(size_t)row*512 + col] = (dacc[nt2][reg]-mean[reg])*rstd[reg]*gg + bb2;
            }
        }
    }
}

extern "C" void kernel_launch(void* const* d_in, const int* in_sizes, int n_in,
                              void* d_out, int out_size, void* d_ws, size_t ws_size,
                              hipStream_t stream) {
    (void)in_sizes; (void)n_in; (void)out_size; (void)ws_size;
    const float* x  = (const float*)d_in[0];
    const float* wq = (const float*)d_in[1];
    const float* bq = (const float*)d_in[2];
    const float* wk = (const float*)d_in[3];
    const float* bk = (const float*)d_in[4];
    const float* wv = (const float*)d_in[5];
    const float* bv = (const float*)d_in[6];
    const float* wm = (const float*)d_in[7];
    const float* bm = (const float*)d_in[8];
    const float* g1 = (const float*)d_in[9];
    const float* b1 = (const float*)d_in[10];
    const float* g2 = (const float*)d_in[11];
    const float* b2 = (const float*)d_in[12];

    // ws layout (11.67 MB, same total as v1): bf16 frag panels
    u16* wqkv_p = (u16*)d_ws;                  // 640 KB (16 s x 40 nt x 512)
    u16* wm_p   = wqkv_p + 327680;             // 512 KB
    u16* Qb     = wm_p   + 262144;             // 1 MB  (512 rt x 1024)
    u16* Kb     = Qb     + 524288;             // 1 MB
    u16* Vb     = Kb     + 524288;             // 8 MB  (32 bd x 8 s x 16384)
    float* outp = (float*)d_out;

    k0_prep<<<64, 256, 0, stream>>>(wq, wk, wv, wm, wqkv_p, wm_p);
    k1_qkv <<<256, 512, 0, stream>>>(x, bq, bk, wqkv_p, Qb, Kb, Vb);
    k234   <<<256, 512, 0, stream>>>(Qb, Kb, Vb, wm_p, x, bv, g1, b1, bm, g2, b2, outp);
}

// Round 2
// 143.900 us; speedup vs baseline: 1.0632x; 1.0607x over previous
//
#include <hip/hip_runtime.h>
#include <cstdint>

// B,D,H,W,C = 4,8,16,16,512; R=64; F=256; rows=8192; keys/batch=2048.
// v3: counted-vmcnt pipeline (T3+T4) + setprio (T5).
//   Hot K-loops use raw s_barrier + s_waitcnt vmcnt(G): prefetch loads for
//   chunk s+1 stay IN FLIGHT across the barrier (no vmcnt(0) drain — the
//   __syncthreads drain was the round-1 bottleneck).
//   Phase A: 8 chunks x 256 keys (was 16 x 128) — half the barrier rounds.
//   k0: weight packing; k1: fused QKV GEMM; k234: attn+LN+MLP+LN fused.
#define LN_EPS 1e-3f
using u16 = unsigned short;
using u32 = unsigned int;
typedef __attribute__((ext_vector_type(8))) short bh8;   // 8 bf16
typedef __attribute__((ext_vector_type(4))) float f4;    // 4 f32 acc
#define MFMA16(A,B,C) __builtin_amdgcn_mfma_f32_16x16x32_bf16((A),(B),(C),0,0,0)
#define SBAR() __builtin_amdgcn_s_barrier()
#define CFENCE() asm volatile("" ::: "memory")
#define WAITV(N) asm volatile("s_waitcnt vmcnt(" #N ")" ::: "memory")

__device__ __forceinline__ u16 bf16r(float f){
    union{float f;u32 u;} c; c.f=f;
    return (u16)((c.u + 0x7fffu + ((c.u>>16)&1u))>>16);
}
__device__ __forceinline__ u32 pk2(float a, float b){
    return (u32)bf16r(a) | ((u32)bf16r(b)<<16);
}
__device__ __forceinline__ void glds16(const void* g, void* l){
    __builtin_amdgcn_global_load_lds(
        (const __attribute__((address_space(1))) u32*)g,
        (__attribute__((address_space(3))) u32*)l, 16, 0, 0);
}

// ---------------- K0: pack weights -> bf16 frag-ordered B panels ----------------
__global__ __launch_bounds__(256) void k0_prep(
    const float* __restrict__ wq, const float* __restrict__ wk,
    const float* __restrict__ wv, const float* __restrict__ wm,
    u16* __restrict__ wqkv_p, u16* __restrict__ wm_p)
{
    const int t = threadIdx.x;
    const int c = t & 15, qn = t >> 4;
    const int quad = qn & 3, ntl = qn >> 2;   // ntl 0..3
    const int blk = blockIdx.x;
    if (blk < 32){
        const int s = blk >> 1, hh = blk & 1;
        const int krow = s*32 + quad*8;
        u16* dst = wqkv_p + (size_t)s*20480;
        #pragma unroll
        for (int i=0;i<5;++i){
            const int nt = hh*20 + i*4 + ntl;
            const int n = nt*16 + c;
            const float* src; int ldw;
            if (n < 64){ src = wq + (size_t)krow*64 + n; ldw = 64; }
            else if (n < 128){ src = wk + (size_t)krow*64 + (n-64); ldw = 64; }
            else { src = wv + (size_t)krow*512 + (n-128); ldw = 512; }
            float v[8];
            #pragma unroll
            for (int j=0;j<8;++j) v[j] = src[(size_t)j*ldw];
            uint4 o; o.x=pk2(v[0],v[1]); o.y=pk2(v[2],v[3]); o.z=pk2(v[4],v[5]); o.w=pk2(v[6],v[7]);
            *(uint4*)&dst[((nt*4+quad)*16 + c)*8] = o;
        }
    } else {
        const int bb = blk - 32;
        const int s = bb >> 1, hh = bb & 1;
        const int krow = s*32 + quad*8;
        u16* dst = wm_p + (size_t)s*16384;
        #pragma unroll
        for (int i=0;i<4;++i){
            const int nt = hh*16 + i*4 + ntl;
            const int n = nt*16 + c;
            const float* src = wm + (size_t)krow*512 + n;
            float v[8];
            #pragma unroll
            for (int j=0;j<8;++j) v[j] = src[(size_t)j*512];
            uint4 o; o.x=pk2(v[0],v[1]); o.y=pk2(v[2],v[3]); o.z=pk2(v[4],v[5]); o.w=pk2(v[6],v[7]);
            *(uint4*)&dst[((nt*4+quad)*16 + c)*8] = o;
        }
    }
}

// ---------------- K1: fused QKV projection ----------------
// 256 blocks x 512 thr; 32 rows/block; N=640 (Q64|K64|V512); K=512 in 16 steps.
__global__ __launch_bounds__(512) void k1_qkv(
    const float* __restrict__ x, const float* __restrict__ bq, const float* __restrict__ bk,
    const u16* __restrict__ wqkv_p,
    u16* __restrict__ Qb, u16* __restrict__ Kb, u16* __restrict__ Vb)
{
    __shared__ u16 Asf[16384];      // 32 KB: 2 rg-tiles x 16 s x 512 (A frags)
    __shared__ u16 Bs[2][20480];    // 2 x 40 KB ring
    const int t = threadIdx.x, w = t>>6, lane = t&63, quad = (lane>>4)&3, c = lane&15;
    const int rg = w>>2, cg = w&3;
    const int rowbase = blockIdx.x << 5;

    // prologue: chunk 0 issued first (overlaps with A-staging)
    #pragma unroll
    for (int i=0;i<5;++i)
        glds16((const char*)wqkv_p + (size_t)w*5120 + i*1024 + lane*16,
               (char*)Bs[0] + w*5120 + i*1024);
    // stage A (32 rows x 512 f32 -> bf16 frag order), coalesced float4
    #pragma unroll
    for (int i=0;i<8;++i){
        const int idx = t + (i<<9);            // 0..4095 float4 units
        const int fr = idx >> 7, fc4 = idx & 127;
        float4 xv = *(const float4*)&x[(size_t)(rowbase+fr)*512 + fc4*4];
        uint2 pkv; pkv.x = pk2(xv.x,xv.y); pkv.y = pk2(xv.z,xv.w);
        const int s = fc4 >> 3, qd = (fc4 >> 1) & 3, j0 = (fc4 & 1)*4;
        *(uint2*)&Asf[(fr>>4)*8192 + s*512 + (qd*16 + (fr&15))*8 + j0] = pkv;
    }
    f4 acc[10];
    #pragma unroll
    for (int i=0;i<10;++i) acc[i] = (f4){0.f,0.f,0.f,0.f};
    __syncthreads();                // drains everything; vm count = 0 here

    for (int s=0;s<16;++s){
        const u16* Bcur = Bs[s&1];
        bh8 a = *(const bh8*)&Asf[rg*8192 + s*512 + (quad*16+c)*8];
        if (s+1 < 16){
            #pragma unroll
            for (int i=0;i<5;++i)
                glds16((const char*)wqkv_p + (size_t)(s+1)*40960 + (size_t)w*5120 + i*1024 + lane*16,
                       (char*)Bs[(s+1)&1] + w*5120 + i*1024);
            WAITV(5);               // buf[s] loads done; buf[s+1] stays in flight
        } else {
            WAITV(0);
        }
        SBAR(); CFENCE();
        __builtin_amdgcn_s_setprio(1);
        #pragma unroll
        for (int nt2=0;nt2<10;++nt2){
            bh8 bb = *(const bh8*)&Bcur[((cg*10+nt2)*4 + quad)*128 + c*8];
            acc[nt2] = MFMA16(a, bb, acc[nt2]);
        }
        __builtin_amdgcn_s_setprio(0);
        CFENCE(); SBAR();
    }

    // epilogue: Q/K -> frag panels (+bias); V -> B-operand frag layout (no bias)
    const int rt = (blockIdx.x<<1) + rg;
    const int bd = rowbase >> 8;
    const int kloc = (rowbase & 255) + rg*16 + quad*4;     // + reg
    const int sv = kloc >> 5, kq = (kloc >> 3) & 3, jk0 = kloc & 7;  // reg-invariant
    #pragma unroll
    for (int nt2=0;nt2<10;++nt2){
        const int colb = cg*160 + nt2*16;
        if (colb < 128){
            const bool isK = (colb >= 64);
            const int r = colb - (isK ? 64 : 0) + c;
            const float bias = isK ? bk[r] : bq[r];
            u16* dstb = (isK ? Kb : Qb) + ((size_t)(rt*2 + (r>>5))*4 + ((r>>3)&3))*128 + (r&7);
            #pragma unroll
            for (int reg=0;reg<4;++reg)
                dstb[(quad*4+reg)*8] = bf16r(acc[nt2][reg] + bias);
        } else {
            const int ntv = (colb - 128) >> 4;             // channel group; cv = c
            u16* dstv = Vb + (size_t)bd*131072 + (size_t)sv*16384
                           + (size_t)((ntv*4+kq)*128 + c*8 + jk0);
            ushort4 o;
            o.x = bf16r(acc[nt2][0]); o.y = bf16r(acc[nt2][1]);
            o.z = bf16r(acc[nt2][2]); o.w = bf16r(acc[nt2][3]);
            *(ushort4*)dstv = o;
        }
    }
}

// ---------------- K234: scores+softmax-fold, a2@V, LN, y1@wm, LN ----------------
// 256 blocks x 512 thr (8 waves = 2rg x 4cg), 32 rows/block.
__global__ __launch_bounds__(512) void k234(
    const u16* __restrict__ Qb, const u16* __restrict__ Kb, const u16* __restrict__ Vb,
    const u16* __restrict__ wm_p,
    const float* __restrict__ x, const float* __restrict__ bv,
    const float* __restrict__ g1, const float* __restrict__ b1,
    const float* __restrict__ bm, const float* __restrict__ g2, const float* __restrict__ b2,
    float* __restrict__ out)
{
    __shared__ u16 Bs[2][16384];    // 64 KB ring (32 KB per buffer)
    __shared__ u16 y1f[16384];      // 32 KB: y1 A-frags, 2 rg x 16 s x 512
    __shared__ u16 a2f[8192];       // 16 KB: a2 A-frags, 2 rg x 8 s x 512
    __shared__ u16 qsf[2048];       // 4 KB: Q frags, 2 rts
    __shared__ float redA[2][4][16], redB[2][4][16];
    const int t = threadIdx.x, w = t>>6, lane = t&63, quad = (lane>>4)&3, c = lane&15;
    const int rg = w>>2, cg = w&3;
    const int bd = blockIdx.x & 31, ftile = blockIdx.x >> 5;   // XCD-aligned decode
    const int b = bd >> 3;
    const int rowbase = (bd<<8) + (ftile<<5);
    const int rt00 = rowbase >> 4;
    const char* Kbase = (const char*)Kb + (size_t)b*262144;
    const char* Vbase = (const char*)Vb + (size_t)bd*262144;

    // ---- Phase A prologue: Q frags + key-chunk 0 (256 keys = 32 KB)
    if (w < 4) glds16((const char*)Qb + (size_t)rt00*2048 + w*1024 + lane*16,
                      (char*)qsf + w*1024);
    #pragma unroll
    for (int i=0;i<4;++i)
        glds16(Kbase + (size_t)w*4096 + i*1024 + lane*16, (char*)Bs[0] + w*4096 + i*1024);
    __syncthreads();                // drained; vm count = 0
    bh8 aq0 = *(const bh8*)&qsf[rg*1024 + (quad*16+c)*8];
    bh8 aq1 = *(const bh8*)&qsf[rg*1024 + 512 + (quad*16+c)*8];

    float lp[4] = {0.f,0.f,0.f,0.f};
    float a2r[4][4] = {};
    // ---- Phase A: 8 chunks x 256 keys; exp + g-fold
    for (int cc=0; cc<8; ++cc){
        const u16* Bcur = Bs[cc&1];
        if (cc+1 < 8){
            #pragma unroll
            for (int i=0;i<4;++i)
                glds16(Kbase + (size_t)(cc+1)*32768 + (size_t)w*4096 + i*1024 + lane*16,
                       (char*)Bs[(cc+1)&1] + w*4096 + i*1024);
            WAITV(4);
        } else {
            WAITV(0);
        }
        SBAR(); CFENCE();
        __builtin_amdgcn_s_setprio(1);
        f4 sa[4];
        #pragma unroll
        for (int kt=0;kt<4;++kt){
            sa[kt] = (f4){0.f,0.f,0.f,0.f};
            bh8 b0 = *(const bh8*)&Bcur[(cg*4+kt)*1024 + (quad*16+c)*8];
            bh8 bv1= *(const bh8*)&Bcur[(cg*4+kt)*1024 + 512 + (quad*16+c)*8];
            sa[kt] = MFMA16(aq0, b0, sa[kt]);
            sa[kt] = MFMA16(aq1, bv1, sa[kt]);
        }
        __builtin_amdgcn_s_setprio(0);
        #pragma unroll
        for (int kt=0;kt<4;++kt)
            #pragma unroll
            for (int reg=0;reg<4;++reg){
                float e = __expf(sa[kt][reg]);
                lp[reg] += e;
                a2r[reg][kt] += e;
            }
        CFENCE(); SBAR();
    }
    // prologue for phase B (V chunk 0) -- overlaps softmax finish
    #pragma unroll
    for (int i=0;i<4;++i)
        glds16(Vbase + (size_t)w*4096 + i*1024 + lane*16, (char*)Bs[0] + w*4096 + i*1024);
    // softmax denominator: reduce over c lanes, then across 4 cg waves
    #pragma unroll
    for (int reg=0;reg<4;++reg){
        float v = lp[reg];
        v += __shfl_xor(v,1,64); v += __shfl_xor(v,2,64);
        v += __shfl_xor(v,4,64); v += __shfl_xor(v,8,64);
        lp[reg] = v;
    }
    if (c==0){
        #pragma unroll
        for (int reg=0;reg<4;++reg) redA[rg][cg][quad*4+reg] = lp[reg];
    }
    __syncthreads();
    float fac[4];
    #pragma unroll
    for (int reg=0;reg<4;++reg){
        const int q = quad*4+reg;
        fac[reg] = 1.f/(redA[rg][0][q]+redA[rg][1][q]+redA[rg][2][q]+redA[rg][3][q]);
    }
    #pragma unroll
    for (int reg=0;reg<4;++reg)
        #pragma unroll
        for (int kt=0;kt<4;++kt){
            const int jp = cg*64 + kt*16 + c;
            a2f[rg*4096 + (jp>>5)*512 + (((jp>>3)&3)*16 + quad*4+reg)*8 + (jp&7)]
                = bf16r(a2r[reg][kt]*fac[reg]);
        }
    __syncthreads();                // drains phase-B prologue too; vm count = 0

    // ---- Phase B: attn = a2 @ V  (K=256, 8 steps)
    f4 cacc[8];
    #pragma unroll
    for (int i=0;i<8;++i) cacc[i] = (f4){0.f,0.f,0.f,0.f};
    for (int s8=0;s8<8;++s8){
        const u16* Bcur = Bs[s8&1];
        bh8 a = *(const bh8*)&a2f[rg*4096 + s8*512 + (quad*16+c)*8];
        if (s8+1 < 8){
            #pragma unroll
            for (int i=0;i<4;++i)
                glds16(Vbase + (size_t)(s8+1)*32768 + (size_t)w*4096 + i*1024 + lane*16,
                       (char*)Bs[(s8+1)&1] + w*4096 + i*1024);
            WAITV(4);
        } else {
            WAITV(0);
        }
        SBAR(); CFENCE();
        __builtin_amdgcn_s_setprio(1);
        #pragma unroll
        for (int nt2=0;nt2<8;++nt2){
            bh8 bb = *(const bh8*)&Bcur[((cg*8+nt2)*4 + quad)*128 + c*8];
            cacc[nt2] = MFMA16(a, bb, cacc[nt2]);
        }
        __builtin_amdgcn_s_setprio(0);
        CFENCE(); SBAR();
    }

    // ---- epilogue 1: + bv + x residual, LN -> y1 (kept f32 in cacc, bf16 frags in y1f)
    {
        float sv4[4] = {0.f,0.f,0.f,0.f}, qv2[4] = {0.f,0.f,0.f,0.f};
        #pragma unroll
        for (int nt2=0;nt2<8;++nt2){
            const int col = cg*128 + nt2*16 + c;
            const float bvv = bv[col];
            #pragma unroll
            for (int reg=0;reg<4;++reg){
                const int row = rowbase + rg*16 + quad*4 + reg;
                float val = cacc[nt2][reg] + bvv + x[(size_t)row*512 + col];
                cacc[nt2][reg] = val;
                sv4[reg] += val; qv2[reg] = fmaf(val,val,qv2[reg]);
            }
        }
        #pragma unroll
        for (int reg=0;reg<4;++reg){
            float s1=sv4[reg], s2=qv2[reg];
            s1 += __shfl_xor(s1,1,64); s2 += __shfl_xor(s2,1,64);
            s1 += __shfl_xor(s1,2,64); s2 += __shfl_xor(s2,2,64);
            s1 += __shfl_xor(s1,4,64); s2 += __shfl_xor(s2,4,64);
            s1 += __shfl_xor(s1,8,64); s2 += __shfl_xor(s2,8,64);
            sv4[reg]=s1; qv2[reg]=s2;
        }
        if (c==0){
            #pragma unroll
            for (int reg=0;reg<4;++reg){ redA[rg][cg][quad*4+reg]=sv4[reg]; redB[rg][cg][quad*4+reg]=qv2[reg]; }
        }
        __syncthreads();
        float mean[4], rstd[4];
        #pragma unroll
        for (int reg=0;reg<4;++reg){
            const int q = quad*4+reg;
            const float S  = redA[rg][0][q]+redA[rg][1][q]+redA[rg][2][q]+redA[rg][3][q];
            const float Q2 = redB[rg][0][q]+redB[rg][1][q]+redB[rg][2][q]+redB[rg][3][q];
            const float m = S*(1.f/512.f);
            mean[reg]=m; rstd[reg]=rsqrtf(Q2*(1.f/512.f) - m*m + LN_EPS);
        }
        #pragma unroll
        for (int nt2=0;nt2<8;++nt2){
            const int col = cg*128 + nt2*16 + c;
            const float gg = g1[col], bb1 = b1[col];
            #pragma unroll
            for (int reg=0;reg<4;++reg){
                float y = (cacc[nt2][reg]-mean[reg])*rstd[reg]*gg + bb1;
                cacc[nt2][reg] = y;
                y1f[rg*8192 + (col>>5)*512 + (((col>>3)&3)*16 + quad*4+reg)*8 + (col&7)] = bf16r(y);
            }
        }
        // prologue for phase D (wm chunk 0) -- drained by the syncthreads below
        #pragma unroll
        for (int i=0;i<4;++i)
            glds16((const char*)wm_p + (size_t)w*4096 + i*1024 + lane*16,
                   (char*)Bs[0] + w*4096 + i*1024);
        __syncthreads();            // vm count = 0
    }

    // ---- Phase D: mlp = y1 @ wm (K=512, 16 steps)
    f4 dacc[8];
    #pragma unroll
    for (int i=0;i<8;++i) dacc[i] = (f4){0.f,0.f,0.f,0.f};
    for (int s=0;s<16;++s){
        const u16* Bcur = Bs[s&1];
        bh8 a = *(const bh8*)&y1f[rg*8192 + s*512 + (quad*16+c)*8];
        if (s+1 < 16){
            #pragma unroll
            for (int i=0;i<4;++i)
                glds16((const char*)wm_p + (size_t)(s+1)*32768 + (size_t)w*4096 + i*1024 + lane*16,
                       (char*)Bs[(s+1)&1] + w*4096 + i*1024);
            WAITV(4);
        } else {
            WAITV(0);
        }
        SBAR(); CFENCE();
        __builtin_amdgcn_s_setprio(1);
        #pragma unroll
        for (int nt2=0;nt2<8;++nt2){
            bh8 bb = *(const bh8*)&Bcur[((cg*8+nt2)*4 + quad)*128 + c*8];
            dacc[nt2] = MFMA16(a, bb, dacc[nt2]);
        }
        __builtin_amdgcn_s_setprio(0);
        CFENCE(); SBAR();
    }

    // ---- epilogue 2: relu(+bm) + y1 residual, LN -> out
    {
        float sv4[4] = {0.f,0.f,0.f,0.f}, qv2[4] = {0.f,0.f,0.f,0.f};
        #pragma unroll
        for (int nt2=0;nt2<8;++nt2){
            const int col = cg*128 + nt2*16 + c;
            const float bmv = bm[col];
            #pragma unroll
            for (int reg=0;reg<4;++reg){
                float hh = fmaxf(dacc[nt2][reg]+bmv, 0.f) + cacc[nt2][reg];
                dacc[nt2][reg] = hh;
                sv4[reg] += hh; qv2[reg] = fmaf(hh,hh,qv2[reg]);
            }
        }
        #pragma unroll
        for (int reg=0;reg<4;++reg){
            float s1=sv4[reg], s2=qv2[reg];
            s1 += __shfl_xor(s1,1,64); s2 += __shfl_xor(s2,1,64);
            s1 += __shfl_xor(s1,2,64); s2 += __shfl_xor(s2,2,64);
            s1 += __shfl_xor(s1,4,64); s2 += __shfl_xor(s2,4,64);
            s1 += __shfl_xor(s1,8,64); s2 += __shfl_xor(s2,8,64);
            sv4[reg]=s1; qv2[reg]=s2;
        }
        if (c==0){
            #pragma unroll
            for (int reg=0;reg<4;++reg){ redA[rg][cg][quad*4+reg]=sv4[reg]; redB[rg][cg][quad*4+reg]=qv2[reg]; }
        }
        __syncthreads();
        float mean[4], rstd[4];
        #pragma unroll
        for (int reg=0;reg<4;++reg){
            const int q = quad*4+reg;
            const float S  = redA[rg][0][q]+redA[rg][1][q]+redA[rg][2][q]+redA[rg][3][q];
            const float Q2 = redB[rg][0][q]+redB[rg][1][q]+redB[rg][2][q]+redB[rg][3][q];
            const float m = S*(1.f/512.f);
            mean[reg]=m; rstd[reg]=rsqrtf(Q2*(1.f/512.f) - m*m + LN_EPS);
        }
        #pragma unroll
        for (int nt2=0;nt2<8;++nt2){
            const int col = cg*128 + nt2*16 + c;
            const float gg = g2[col], bb2 = b2[col];
            #pragma unroll
            for (int reg=0;reg<4;++reg){
                const int row = rowbase + rg*16 + quad*4 + reg;
                out[(size_t)row*512 + col] = (dacc[nt2][reg]-mean[reg])*rstd[reg]*gg + bb2;
            }
        }
    }
}

extern "C" void kernel_launch(void* const* d_in, const int* in_sizes, int n_in,
                              void* d_out, int out_size, void* d_ws, size_t ws_size,
                              hipStream_t stream) {
    (void)in_sizes; (void)n_in; (void)out_size; (void)ws_size;
    const float* x  = (const float*)d_in[0];
    const float* wq = (const float*)d_in[1];
    const float* bq = (const float*)d_in[2];
    const float* wk = (const float*)d_in[3];
    const float* bk = (const float*)d_in[4];
    const float* wv = (const float*)d_in[5];
    const float* bv = (const float*)d_in[6];
    const float* wm = (const float*)d_in[7];
    const float* bm = (const float*)d_in[8];
    const float* g1 = (const float*)d_in[9];
    const float* b1 = (const float*)d_in[10];
    const float* g2 = (const float*)d_in[11];
    const float* b2 = (const float*)d_in[12];

    // ws layout (11.67 MB): bf16 frag panels
    u16* wqkv_p = (u16*)d_ws;                  // 640 KB (16 s x 40 nt x 512)
    u16* wm_p   = wqkv_p + 327680;             // 512 KB
    u16* Qb     = wm_p   + 262144;             // 1 MB  (512 rt x 1024)
    u16* Kb     = Qb     + 524288;             // 1 MB
    u16* Vb     = Kb     + 524288;             // 8 MB  (32 bd x 8 s x 16384)
    float* outp = (float*)d_out;

    k0_prep<<<64, 256, 0, stream>>>(wq, wk, wv, wm, wqkv_p, wm_p);
    k1_qkv <<<256, 512, 0, stream>>>(x, bq, bk, wqkv_p, Qb, Kb, Vb);
    k234   <<<256, 512, 0, stream>>>(Qb, Kb, Vb, wm_p, x, bv, g1, b1, bm, g2, b2, outp);
}

// Round 3
// 140.192 us; speedup vs baseline: 1.0914x; 1.0264x over previous
//
#include <hip/hip_runtime.h>
#include <cstdint>

// B,D,H,W,C = 4,8,16,16,512; R=64; F=256; rows=8192; keys/batch=2048.
// v4: 3-buffer 2-deep counted-vmcnt pipeline (T3+T4 deepened) + setprio (T5).
//   Uniform step rule: issue chunk s+2 into Bs[(s+2)%3]; WAITV(2G) -> chunk s
//   complete, chunks s+1/s+2 in flight. Phase boundaries keep prefetch alive:
//   next phase's chunks 0,1 issued before the epilogue; epilogue barriers are
//   lgkmcnt(0)+s_barrier (NOT __syncthreads' vmcnt(0) drain).
#define LN_EPS 1e-3f
using u16 = unsigned short;
using u32 = unsigned int;
typedef __attribute__((ext_vector_type(8))) short bh8;   // 8 bf16
typedef __attribute__((ext_vector_type(4))) float f4;    // 4 f32 acc
#define MFMA16(A,B,C) __builtin_amdgcn_mfma_f32_16x16x32_bf16((A),(B),(C),0,0,0)
#define SBAR() __builtin_amdgcn_s_barrier()
#define CFENCE() asm volatile("" ::: "memory")
#define WAITV(N) asm volatile("s_waitcnt vmcnt(" #N ")" ::: "memory")
#define LKBAR() do{ asm volatile("s_waitcnt lgkmcnt(0)" ::: "memory"); \
                    __builtin_amdgcn_s_barrier(); asm volatile("" ::: "memory"); }while(0)

__device__ __forceinline__ u16 bf16r(float f){
    union{float f;u32 u;} c; c.f=f;
    return (u16)((c.u + 0x7fffu + ((c.u>>16)&1u))>>16);
}
__device__ __forceinline__ u32 pk2(float a, float b){
    return (u32)bf16r(a) | ((u32)bf16r(b)<<16);
}
__device__ __forceinline__ void glds16(const void* g, void* l){
    __builtin_amdgcn_global_load_lds(
        (const __attribute__((address_space(1))) u32*)g,
        (__attribute__((address_space(3))) u32*)l, 16, 0, 0);
}

// ---------------- K0: pack weights -> bf16 frag-ordered B panels ----------------
__global__ __launch_bounds__(256) void k0_prep(
    const float* __restrict__ wq, const float* __restrict__ wk,
    const float* __restrict__ wv, const float* __restrict__ wm,
    u16* __restrict__ wqkv_p, u16* __restrict__ wm_p)
{
    const int t = threadIdx.x;
    const int c = t & 15, qn = t >> 4;
    const int quad = qn & 3, ntl = qn >> 2;   // ntl 0..3
    const int blk = blockIdx.x;
    if (blk < 32){
        const int s = blk >> 1, hh = blk & 1;
        const int krow = s*32 + quad*8;
        u16* dst = wqkv_p + (size_t)s*20480;
        #pragma unroll
        for (int i=0;i<5;++i){
            const int nt = hh*20 + i*4 + ntl;
            const int n = nt*16 + c;
            const float* src; int ldw;
            if (n < 64){ src = wq + (size_t)krow*64 + n; ldw = 64; }
            else if (n < 128){ src = wk + (size_t)krow*64 + (n-64); ldw = 64; }
            else { src = wv + (size_t)krow*512 + (n-128); ldw = 512; }
            float v[8];
            #pragma unroll
            for (int j=0;j<8;++j) v[j] = src[(size_t)j*ldw];
            uint4 o; o.x=pk2(v[0],v[1]); o.y=pk2(v[2],v[3]); o.z=pk2(v[4],v[5]); o.w=pk2(v[6],v[7]);
            *(uint4*)&dst[((nt*4+quad)*16 + c)*8] = o;
        }
    } else {
        const int bb = blk - 32;
        const int s = bb >> 1, hh = bb & 1;
        const int krow = s*32 + quad*8;
        u16* dst = wm_p + (size_t)s*16384;
        #pragma unroll
        for (int i=0;i<4;++i){
            const int nt = hh*16 + i*4 + ntl;
            const int n = nt*16 + c;
            const float* src = wm + (size_t)krow*512 + n;
            float v[8];
            #pragma unroll
            for (int j=0;j<8;++j) v[j] = src[(size_t)j*512];
            uint4 o; o.x=pk2(v[0],v[1]); o.y=pk2(v[2],v[3]); o.z=pk2(v[4],v[5]); o.w=pk2(v[6],v[7]);
            *(uint4*)&dst[((nt*4+quad)*16 + c)*8] = o;
        }
    }
}

// ---------------- K1: fused QKV projection ----------------
// 256 blocks x 512 thr; 32 rows/block; N=640 (Q64|K64|V512); K=512 in 16 steps.
__global__ __launch_bounds__(512) void k1_qkv(
    const float* __restrict__ x, const float* __restrict__ bq, const float* __restrict__ bk,
    const u16* __restrict__ wqkv_p,
    u16* __restrict__ Qb, u16* __restrict__ Kb, u16* __restrict__ Vb)
{
    __shared__ u16 Asf[16384];      // 32 KB: 2 rg-tiles x 16 s x 512 (A frags)
    __shared__ u16 Bs[3][20480];    // 3 x 40 KB ring
    const int t = threadIdx.x, w = t>>6, lane = t&63, quad = (lane>>4)&3, c = lane&15;
    const int rg = w>>2, cg = w&3;
    const int rowbase = blockIdx.x << 5;

    // prologue: chunks 0,1 in flight (overlap with A-staging x loads)
    #pragma unroll
    for (int i=0;i<5;++i)
        glds16((const char*)wqkv_p + (size_t)w*5120 + i*1024 + lane*16,
               (char*)Bs[0] + w*5120 + i*1024);
    #pragma unroll
    for (int i=0;i<5;++i)
        glds16((const char*)wqkv_p + 40960 + (size_t)w*5120 + i*1024 + lane*16,
               (char*)Bs[1] + w*5120 + i*1024);
    // stage A (32 rows x 512 f32 -> bf16 frag order), coalesced float4
    #pragma unroll
    for (int i=0;i<8;++i){
        const int idx = t + (i<<9);            // 0..4095 float4 units
        const int fr = idx >> 7, fc4 = idx & 127;
        float4 xv = *(const float4*)&x[(size_t)(rowbase+fr)*512 + fc4*4];
        uint2 pkv; pkv.x = pk2(xv.x,xv.y); pkv.y = pk2(xv.z,xv.w);
        const int s = fc4 >> 3, qd = (fc4 >> 1) & 3, j0 = (fc4 & 1)*4;
        *(uint2*)&Asf[(fr>>4)*8192 + s*512 + (qd*16 + (fr&15))*8 + j0] = pkv;
    }
    f4 acc[10];
    #pragma unroll
    for (int i=0;i<10;++i) acc[i] = (f4){0.f,0.f,0.f,0.f};
    LKBAR();                        // A-frags visible; vm prefetch NOT drained

    #pragma unroll
    for (int s=0;s<16;++s){
        const u16* Bcur = Bs[s%3];
        bh8 a = *(const bh8*)&Asf[rg*8192 + s*512 + (quad*16+c)*8];
        if (s+2 < 16){
            #pragma unroll
            for (int i=0;i<5;++i)
                glds16((const char*)wqkv_p + (size_t)(s+2)*40960 + (size_t)w*5120 + i*1024 + lane*16,
                       (char*)Bs[(s+2)%3] + w*5120 + i*1024);
            WAITV(10);              // chunk s complete; s+1,s+2 in flight
        } else if (s+1 < 16){
            WAITV(5);
        } else {
            WAITV(0);
        }
        SBAR(); CFENCE();
        __builtin_amdgcn_s_setprio(1);
        #pragma unroll
        for (int nt2=0;nt2<10;++nt2){
            bh8 bb = *(const bh8*)&Bcur[((cg*10+nt2)*4 + quad)*128 + c*8];
            acc[nt2] = MFMA16(a, bb, acc[nt2]);
        }
        __builtin_amdgcn_s_setprio(0);
        CFENCE(); SBAR();
    }

    // epilogue: Q/K -> frag panels (+bias); V -> B-operand frag layout (no bias)
    const int rt = (blockIdx.x<<1) + rg;
    const int bd = rowbase >> 8;
    const int kloc = (rowbase & 255) + rg*16 + quad*4;     // + reg
    const int sv = kloc >> 5, kq = (kloc >> 3) & 3, jk0 = kloc & 7;  // reg-invariant
    #pragma unroll
    for (int nt2=0;nt2<10;++nt2){
        const int colb = cg*160 + nt2*16;
        if (colb < 128){
            const bool isK = (colb >= 64);
            const int r = colb - (isK ? 64 : 0) + c;
            const float bias = isK ? bk[r] : bq[r];
            u16* dstb = (isK ? Kb : Qb) + ((size_t)(rt*2 + (r>>5))*4 + ((r>>3)&3))*128 + (r&7);
            #pragma unroll
            for (int reg=0;reg<4;++reg)
                dstb[(quad*4+reg)*8] = bf16r(acc[nt2][reg] + bias);
        } else {
            const int ntv = (colb - 128) >> 4;             // channel group; cv = c
            u16* dstv = Vb + (size_t)bd*131072 + (size_t)sv*16384
                           + (size_t)((ntv*4+kq)*128 + c*8 + jk0);
            ushort4 o;
            o.x = bf16r(acc[nt2][0]); o.y = bf16r(acc[nt2][1]);
            o.z = bf16r(acc[nt2][2]); o.w = bf16r(acc[nt2][3]);
            *(ushort4*)dstv = o;
        }
    }
}

// ---------------- K234: scores+softmax-fold, a2@V, LN, y1@wm, LN ----------------
// 256 blocks x 512 thr (8 waves = 2rg x 4cg), 32 rows/block.
__global__ __launch_bounds__(512) void k234(
    const u16* __restrict__ Qb, const u16* __restrict__ Kb, const u16* __restrict__ Vb,
    const u16* __restrict__ wm_p,
    const float* __restrict__ x, const float* __restrict__ bv,
    const float* __restrict__ g1, const float* __restrict__ b1,
    const float* __restrict__ bm, const float* __restrict__ g2, const float* __restrict__ b2,
    float* __restrict__ out)
{
    __shared__ u16 Bs[3][16384];    // 96 KB ring (32 KB per buffer)
    __shared__ u16 y1f[16384];      // 32 KB: y1 A-frags, 2 rg x 16 s x 512
    __shared__ u16 a2f[8192];       // 16 KB: a2 A-frags, 2 rg x 8 s x 512
    __shared__ u16 qsf[2048];       // 4 KB: Q frags, 2 rts
    __shared__ float redA[2][4][16], redB[2][4][16];
    const int t = threadIdx.x, w = t>>6, lane = t&63, quad = (lane>>4)&3, c = lane&15;
    const int rg = w>>2, cg = w&3;
    const int bd = blockIdx.x & 31, ftile = blockIdx.x >> 5;   // XCD-aligned decode
    const int b = bd >> 3;
    const int rowbase = (bd<<8) + (ftile<<5);
    const int rt00 = rowbase >> 4;
    const char* Kbase = (const char*)Kb + (size_t)b*262144;
    const char* Vbase = (const char*)Vb + (size_t)bd*262144;

    // ---- Phase A prologue: Q frags + key-chunks 0,1 (2 x 32 KB in flight)
    if (w < 4) glds16((const char*)Qb + (size_t)rt00*2048 + w*1024 + lane*16,
                      (char*)qsf + w*1024);
    #pragma unroll
    for (int i=0;i<4;++i)
        glds16(Kbase + (size_t)w*4096 + i*1024 + lane*16, (char*)Bs[0] + w*4096 + i*1024);
    #pragma unroll
    for (int i=0;i<4;++i)
        glds16(Kbase + 32768 + (size_t)w*4096 + i*1024 + lane*16, (char*)Bs[1] + w*4096 + i*1024);
    WAITV(8);                       // Q load (oldest, waves 0-3) complete
    SBAR(); CFENCE();               // qsf visible to all waves
    bh8 aq0 = *(const bh8*)&qsf[rg*1024 + (quad*16+c)*8];
    bh8 aq1 = *(const bh8*)&qsf[rg*1024 + 512 + (quad*16+c)*8];

    float lp[4] = {0.f,0.f,0.f,0.f};
    float a2r[4][4] = {};
    // ---- Phase A: 8 chunks x 256 keys; exp + g-fold
    #pragma unroll
    for (int cc=0; cc<8; ++cc){
        const u16* Bcur = Bs[cc%3];
        if (cc+2 < 8){
            #pragma unroll
            for (int i=0;i<4;++i)
                glds16(Kbase + (size_t)(cc+2)*32768 + (size_t)w*4096 + i*1024 + lane*16,
                       (char*)Bs[(cc+2)%3] + w*4096 + i*1024);
            WAITV(8);
        } else if (cc+1 < 8){
            WAITV(4);
        } else {
            WAITV(0);
        }
        SBAR(); CFENCE();
        __builtin_amdgcn_s_setprio(1);
        f4 sa[4];
        #pragma unroll
        for (int kt=0;kt<4;++kt){
            sa[kt] = (f4){0.f,0.f,0.f,0.f};
            bh8 b0 = *(const bh8*)&Bcur[(cg*4+kt)*1024 + (quad*16+c)*8];
            bh8 bv1= *(const bh8*)&Bcur[(cg*4+kt)*1024 + 512 + (quad*16+c)*8];
            sa[kt] = MFMA16(aq0, b0, sa[kt]);
            sa[kt] = MFMA16(aq1, bv1, sa[kt]);
        }
        __builtin_amdgcn_s_setprio(0);
        #pragma unroll
        for (int kt=0;kt<4;++kt)
            #pragma unroll
            for (int reg=0;reg<4;++reg){
                float e = __expf(sa[kt][reg]);
                lp[reg] += e;
                a2r[reg][kt] += e;
            }
        CFENCE(); SBAR();
    }
    // prefetch V chunks 0,1 -- stays in flight across the softmax epilogue
    #pragma unroll
    for (int i=0;i<4;++i)
        glds16(Vbase + (size_t)w*4096 + i*1024 + lane*16, (char*)Bs[0] + w*4096 + i*1024);
    #pragma unroll
    for (int i=0;i<4;++i)
        glds16(Vbase + 32768 + (size_t)w*4096 + i*1024 + lane*16, (char*)Bs[1] + w*4096 + i*1024);
    // softmax denominator: reduce over c lanes, then across 4 cg waves
    #pragma unroll
    for (int reg=0;reg<4;++reg){
        float v = lp[reg];
        v += __shfl_xor(v,1,64); v += __shfl_xor(v,2,64);
        v += __shfl_xor(v,4,64); v += __shfl_xor(v,8,64);
        lp[reg] = v;
    }
    if (c==0){
        #pragma unroll
        for (int reg=0;reg<4;++reg) redA[rg][cg][quad*4+reg] = lp[reg];
    }
    LKBAR();                        // no vmcnt drain
    float fac[4];
    #pragma unroll
    for (int reg=0;reg<4;++reg){
        const int q = quad*4+reg;
        fac[reg] = 1.f/(redA[rg][0][q]+redA[rg][1][q]+redA[rg][2][q]+redA[rg][3][q]);
    }
    #pragma unroll
    for (int reg=0;reg<4;++reg)
        #pragma unroll
        for (int kt=0;kt<4;++kt){
            const int jp = cg*64 + kt*16 + c;
            a2f[rg*4096 + (jp>>5)*512 + (((jp>>3)&3)*16 + quad*4+reg)*8 + (jp&7)]
                = bf16r(a2r[reg][kt]*fac[reg]);
        }
    LKBAR();                        // a2f visible; V prefetch still in flight

    // ---- Phase B: attn = a2 @ V  (K=256, 8 steps)
    f4 cacc[8];
    #pragma unroll
    for (int i=0;i<8;++i) cacc[i] = (f4){0.f,0.f,0.f,0.f};
    #pragma unroll
    for (int s8=0;s8<8;++s8){
        const u16* Bcur = Bs[s8%3];
        bh8 a = *(const bh8*)&a2f[rg*4096 + s8*512 + (quad*16+c)*8];
        if (s8+2 < 8){
            #pragma unroll
            for (int i=0;i<4;++i)
                glds16(Vbase + (size_t)(s8+2)*32768 + (size_t)w*4096 + i*1024 + lane*16,
                       (char*)Bs[(s8+2)%3] + w*4096 + i*1024);
            WAITV(8);
        } else if (s8+1 < 8){
            WAITV(4);
        } else {
            WAITV(0);
        }
        SBAR(); CFENCE();
        __builtin_amdgcn_s_setprio(1);
        #pragma unroll
        for (int nt2=0;nt2<8;++nt2){
            bh8 bb = *(const bh8*)&Bcur[((cg*8+nt2)*4 + quad)*128 + c*8];
            cacc[nt2] = MFMA16(a, bb, cacc[nt2]);
        }
        __builtin_amdgcn_s_setprio(0);
        CFENCE(); SBAR();
    }

    // prefetch wm chunks 0,1 -- stays in flight across epilogue 1
    #pragma unroll
    for (int i=0;i<4;++i)
        glds16((const char*)wm_p + (size_t)w*4096 + i*1024 + lane*16,
               (char*)Bs[0] + w*4096 + i*1024);
    #pragma unroll
    for (int i=0;i<4;++i)
        glds16((const char*)wm_p + 32768 + (size_t)w*4096 + i*1024 + lane*16,
               (char*)Bs[1] + w*4096 + i*1024);

    // ---- epilogue 1: + bv + x residual, LN -> y1 (f32 in cacc, bf16 frags in y1f)
    {
        float sv4[4] = {0.f,0.f,0.f,0.f}, qv2[4] = {0.f,0.f,0.f,0.f};
        #pragma unroll
        for (int nt2=0;nt2<8;++nt2){
            const int col = cg*128 + nt2*16 + c;
            const float bvv = bv[col];
            #pragma unroll
            for (int reg=0;reg<4;++reg){
                const int row = rowbase + rg*16 + quad*4 + reg;
                float val = cacc[nt2][reg] + bvv + x[(size_t)row*512 + col];
                cacc[nt2][reg] = val;
                sv4[reg] += val; qv2[reg] = fmaf(val,val,qv2[reg]);
            }
        }
        #pragma unroll
        for (int reg=0;reg<4;++reg){
            float s1=sv4[reg], s2=qv2[reg];
            s1 += __shfl_xor(s1,1,64); s2 += __shfl_xor(s2,1,64);
            s1 += __shfl_xor(s1,2,64); s2 += __shfl_xor(s2,2,64);
            s1 += __shfl_xor(s1,4,64); s2 += __shfl_xor(s2,4,64);
            s1 += __shfl_xor(s1,8,64); s2 += __shfl_xor(s2,8,64);
            sv4[reg]=s1; qv2[reg]=s2;
        }
        if (c==0){
            #pragma unroll
            for (int reg=0;reg<4;++reg){ redA[rg][cg][quad*4+reg]=sv4[reg]; redB[rg][cg][quad*4+reg]=qv2[reg]; }
        }
        LKBAR();
        float mean[4], rstd[4];
        #pragma unroll
        for (int reg=0;reg<4;++reg){
            const int q = quad*4+reg;
            const float S  = redA[rg][0][q]+redA[rg][1][q]+redA[rg][2][q]+redA[rg][3][q];
            const float Q2 = redB[rg][0][q]+redB[rg][1][q]+redB[rg][2][q]+redB[rg][3][q];
            const float m = S*(1.f/512.f);
            mean[reg]=m; rstd[reg]=rsqrtf(Q2*(1.f/512.f) - m*m + LN_EPS);
        }
        #pragma unroll
        for (int nt2=0;nt2<8;++nt2){
            const int col = cg*128 + nt2*16 + c;
            const float gg = g1[col], bb1 = b1[col];
            #pragma unroll
            for (int reg=0;reg<4;++reg){
                float y = (cacc[nt2][reg]-mean[reg])*rstd[reg]*gg + bb1;
                cacc[nt2][reg] = y;
                y1f[rg*8192 + (col>>5)*512 + (((col>>3)&3)*16 + quad*4+reg)*8 + (col&7)] = bf16r(y);
            }
        }
        LKBAR();                    // y1f visible; wm prefetch still in flight
    }

    // ---- Phase D: mlp = y1 @ wm (K=512, 16 steps)
    f4 dacc[8];
    #pragma unroll
    for (int i=0;i<8;++i) dacc[i] = (f4){0.f,0.f,0.f,0.f};
    #pragma unroll
    for (int s=0;s<16;++s){
        const u16* Bcur = Bs[s%3];
        bh8 a = *(const bh8*)&y1f[rg*8192 + s*512 + (quad*16+c)*8];
        if (s+2 < 16){
            #pragma unroll
            for (int i=0;i<4;++i)
                glds16((const char*)wm_p + (size_t)(s+2)*32768 + (size_t)w*4096 + i*1024 + lane*16,
                       (char*)Bs[(s+2)%3] + w*4096 + i*1024);
            WAITV(8);
        } else if (s+1 < 16){
            WAITV(4);
        } else {
            WAITV(0);
        }
        SBAR(); CFENCE();
        __builtin_amdgcn_s_setprio(1);
        #pragma unroll
        for (int nt2=0;nt2<8;++nt2){
            bh8 bb = *(const bh8*)&Bcur[((cg*8+nt2)*4 + quad)*128 + c*8];
            dacc[nt2] = MFMA16(a, bb, dacc[nt2]);
        }
        __builtin_amdgcn_s_setprio(0);
        CFENCE(); SBAR();
    }

    // ---- epilogue 2: relu(+bm) + y1 residual, LN -> out
    {
        float sv4[4] = {0.f,0.f,0.f,0.f}, qv2[4] = {0.f,0.f,0.f,0.f};
        #pragma unroll
        for (int nt2=0;nt2<8;++nt2){
            const int col = cg*128 + nt2*16 + c;
            const float bmv = bm[col];
            #pragma unroll
            for (int reg=0;reg<4;++reg){
                float hh = fmaxf(dacc[nt2][reg]+bmv, 0.f) + cacc[nt2][reg];
                dacc[nt2][reg] = hh;
                sv4[reg] += hh; qv2[reg] = fmaf(hh,hh,qv2[reg]);
            }
        }
        #pragma unroll
        for (int reg=0;reg<4;++reg){
            float s1=sv4[reg], s2=qv2[reg];
            s1 += __shfl_xor(s1,1,64); s2 += __shfl_xor(s2,1,64);
            s1 += __shfl_xor(s1,2,64); s2 += __shfl_xor(s2,2,64);
            s1 += __shfl_xor(s1,4,64); s2 += __shfl_xor(s2,4,64);
            s1 += __shfl_xor(s1,8,64); s2 += __shfl_xor(s2,8,64);
            sv4[reg]=s1; qv2[reg]=s2;
        }
        if (c==0){
            #pragma unroll
            for (int reg=0;reg<4;++reg){ redA[rg][cg][quad*4+reg]=sv4[reg]; redB[rg][cg][quad*4+reg]=qv2[reg]; }
        }
        __syncthreads();
        float mean[4], rstd[4];
        #pragma unroll
        for (int reg=0;reg<4;++reg){
            const int q = quad*4+reg;
            const float S  = redA[rg][0][q]+redA[rg][1][q]+redA[rg][2][q]+redA[rg][3][q];
            const float Q2 = redB[rg][0][q]+redB[rg][1][q]+redB[rg][2][q]+redB[rg][3][q];
            const float m = S*(1.f/512.f);
            mean[reg]=m; rstd[reg]=rsqrtf(Q2*(1.f/512.f) - m*m + LN_EPS);
        }
        #pragma unroll
        for (int nt2=0;nt2<8;++nt2){
            const int col = cg*128 + nt2*16 + c;
            const float gg = g2[col], bb2 = b2[col];
            #pragma unroll
            for (int reg=0;reg<4;++reg){
                const int row = rowbase + rg*16 + quad*4 + reg;
                out[(size_t)row*512 + col] = (dacc[nt2][reg]-mean[reg])*rstd[reg]*gg + bb2;
            }
        }
    }
}

extern "C" void kernel_launch(void* const* d_in, const int* in_sizes, int n_in,
                              void* d_out, int out_size, void* d_ws, size_t ws_size,
                              hipStream_t stream) {
    (void)in_sizes; (void)n_in; (void)out_size; (void)ws_size;
    const float* x  = (const float*)d_in[0];
    const float* wq = (const float*)d_in[1];
    const float* bq = (const float*)d_in[2];
    const float* wk = (const float*)d_in[3];
    const float* bk = (const float*)d_in[4];
    const float* wv = (const float*)d_in[5];
    const float* bv = (const float*)d_in[6];
    const float* wm = (const float*)d_in[7];
    const float* bm = (const float*)d_in[8];
    const float* g1 = (const float*)d_in[9];
    const float* b1 = (const float*)d_in[10];
    const float* g2 = (const float*)d_in[11];
    const float* b2 = (const float*)d_in[12];

    // ws layout (11.67 MB): bf16 frag panels
    u16* wqkv_p = (u16*)d_ws;                  // 640 KB (16 s x 40 nt x 512)
    u16* wm_p   = wqkv_p + 327680;             // 512 KB
    u16* Qb     = wm_p   + 262144;             // 1 MB  (512 rt x 1024)
    u16* Kb     = Qb     + 524288;             // 1 MB
    u16* Vb     = Kb     + 524288;             // 8 MB  (32 bd x 8 s x 16384)
    float* outp = (float*)d_out;

    k0_prep<<<64, 256, 0, stream>>>(wq, wk, wv, wm, wqkv_p, wm_p);
    k1_qkv <<<256, 512, 0, stream>>>(x, bq, bk, wqkv_p, Qb, Kb, Vb);
    k234   <<<256, 512, 0, stream>>>(Qb, Kb, Vb, wm_p, x, bv, g1, b1, bm, g2, b2, outp);
}